// Round 7
// baseline (180.673 us; speedup 1.0000x reference)
//
#include <hip/hip_runtime.h>

#define LOG2E 1.44269504088896340736f

// ds_swizzle BitMode: src_lane = ((lane & and) | or) ^ xor (per 32-lane half)
// imm = (xor<<10) | (or<<5) | and     — proven correct in R2.
#define SWZ(v, imm) __int_as_float(__builtin_amdgcn_ds_swizzle(__float_as_int(v), (imm)))

// 16 lanes per batch row (R2-proven layout): lane low4 = q*4 + k,
// q=(lr>>2)&3 gate {0:i,1:f,2:g,3:o} (Keras order), k=lr&3 unit (3 dups 2).
// Each lane activates its own gate column, then ONE ds_swizzle round gathers
// all 12 activated values; c0..c2/h0..h2 are updated fully locally.
// -> one dependent LDS round per step instead of R2's two.
__global__ __launch_bounds__(256, 1)
void lstm_onehop_kernel(const float* __restrict__ X,    // [8192,512,16]
                        const float* __restrict__ Wg,   // [16,12]
                        const float* __restrict__ Ug,   // [3,12]
                        const float* __restrict__ bg,   // [12]
                        const float* __restrict__ Wd,   // [3]
                        const float* __restrict__ bd,   // [1]
                        float* __restrict__ out)        // [8192]
{
    constexpr int T = 512;
    const int tid = threadIdx.x;
    const int lr  = tid & 15;         // lane within row group
    const int q   = (lr >> 2) & 3;    // gate: 0=i,1=f,2=g,3=o (Keras order)
    const int k   = lr & 3;           // unit (3 == duplicate of 2)
    const int kk  = (k == 3) ? 2 : k;
    const int col = q * 3 + kk;
    const int b   = blockIdx.x * 16 + (tid >> 4);

    float w[16];
#pragma unroll
    for (int f = 0; f < 16; ++f) w[f] = Wg[f * 12 + col];
    const float u0 = Ug[0 * 12 + col];
    const float u1 = Ug[1 * 12 + col];
    const float u2 = Ug[2 * 12 + col];
    const float bias = bg[col];
    const float wd0 = Wd[0], wd1 = Wd[1], wd2 = Wd[2], bdv = bd[0];

    // act(z) = pa * rcp(1 + exp2(z*pre)) + pb ; tanh for q==2 (g), else sigmoid
    const bool is_g = (q == 2);
    const float pre = is_g ? (-2.0f * LOG2E) : (-LOG2E);
    const float pa  = is_g ? 2.0f : 1.0f;
    const float pb  = is_g ? -1.0f : 0.0f;

    // Full local state per lane (redundant across the 16 lanes of a row)
    float c0 = 0.f, c1 = 0.f, c2 = 0.f;
    float h0 = 0.f, h1 = 0.f, h2 = 0.f;

    const float4* X4 = reinterpret_cast<const float4*>(X) + (size_t)b * (T * 4);

    // 4-step software pipeline (statically indexed after unroll)
    float4 xb[4][4];
#pragma unroll
    for (int s = 0; s < 4; ++s)
#pragma unroll
        for (int p = 0; p < 4; ++p)
            xb[s][p] = X4[s * 4 + p];

    for (int t0 = 0; t0 < T; t0 += 4) {
#pragma unroll
        for (int s = 0; s < 4; ++s) {
            const float4 v0 = xb[s][0];
            const float4 v1 = xb[s][1];
            const float4 v2 = xb[s][2];
            const float4 v3 = xb[s][3];
            {   // prefetch t0+4+s (clamped; tail redundantly reloads)
                int tn = t0 + 4 + s;
                tn = (tn < T) ? tn : (T - 1);
                const size_t o = (size_t)tn * 4;
                xb[s][0] = X4[o + 0];
                xb[s][1] = X4[o + 1];
                xb[s][2] = X4[o + 2];
                xb[s][3] = X4[o + 3];
            }

            const float xv[16] = {v0.x, v0.y, v0.z, v0.w,
                                  v1.x, v1.y, v1.z, v1.w,
                                  v2.x, v2.y, v2.z, v2.w,
                                  v3.x, v3.y, v3.z, v3.w};
            // x·W (independent of swizzle results — overlaps the LDS wait
            // of the PREVIOUS step inside the unrolled body)
            float zx = bias;
#pragma unroll
            for (int f = 0; f < 16; ++f) zx = fmaf(xv[f], w[f], zx);

            // recurrent part from LOCAL h
            float z = fmaf(h0, u0, zx);
            z = fmaf(h1, u1, z);
            z = fmaf(h2, u2, z);

            // activation of this lane's own gate column
            const float e   = __builtin_amdgcn_exp2f(z * pre);
            const float val = fmaf(pa, __builtin_amdgcn_rcpf(1.0f + e), pb);

            // ONE gather round: all 12 activated gate values.
            // source lane (q'*4 + j), bit4 (row-pair) preserved: and=0x10, or=src.
            const float iv0 = SWZ(val, (0  << 5) | 0x10);
            const float iv1 = SWZ(val, (1  << 5) | 0x10);
            const float iv2 = SWZ(val, (2  << 5) | 0x10);
            const float fv0 = SWZ(val, (4  << 5) | 0x10);
            const float fv1 = SWZ(val, (5  << 5) | 0x10);
            const float fv2 = SWZ(val, (6  << 5) | 0x10);
            const float gv0 = SWZ(val, (8  << 5) | 0x10);
            const float gv1 = SWZ(val, (9  << 5) | 0x10);
            const float gv2 = SWZ(val, (10 << 5) | 0x10);
            const float ov0 = SWZ(val, (12 << 5) | 0x10);
            const float ov1 = SWZ(val, (13 << 5) | 0x10);
            const float ov2 = SWZ(val, (14 << 5) | 0x10);

            // local c/h update (redundant on all 16 lanes)
            c0 = fmaf(fv0, c0, iv0 * gv0);
            c1 = fmaf(fv1, c1, iv1 * gv1);
            c2 = fmaf(fv2, c2, iv2 * gv2);

            const float ec0 = __builtin_amdgcn_exp2f(c0 * (-2.0f * LOG2E));
            const float ec1 = __builtin_amdgcn_exp2f(c1 * (-2.0f * LOG2E));
            const float ec2 = __builtin_amdgcn_exp2f(c2 * (-2.0f * LOG2E));
            h0 = ov0 * fmaf(2.0f, __builtin_amdgcn_rcpf(1.0f + ec0), -1.0f);
            h1 = ov1 * fmaf(2.0f, __builtin_amdgcn_rcpf(1.0f + ec1), -1.0f);
            h2 = ov2 * fmaf(2.0f, __builtin_amdgcn_rcpf(1.0f + ec2), -1.0f);
        }
    }

    if (lr == 0) {
        float acc = bdv;
        acc = fmaf(h0, wd0, acc);
        acc = fmaf(h1, wd1, acc);
        acc = fmaf(h2, wd2, acc);
        const float e = __builtin_amdgcn_exp2f(-LOG2E * acc);
        out[b] = __builtin_amdgcn_rcpf(1.0f + e);
    }
}

extern "C" void kernel_launch(void* const* d_in, const int* in_sizes, int n_in,
                              void* d_out, int out_size, void* d_ws, size_t ws_size,
                              hipStream_t stream) {
    const float* X  = (const float*)d_in[0];
    const float* W  = (const float*)d_in[1];
    const float* U  = (const float*)d_in[2];
    const float* bg = (const float*)d_in[3];
    const float* Wd = (const float*)d_in[4];
    const float* bd = (const float*)d_in[5];
    float* out = (float*)d_out;

    dim3 grid(8192 / 16);   // 512 blocks x 256 threads = 2048 waves
    dim3 block(256);
    hipLaunchKernelGGL(lstm_onehop_kernel, grid, block, 0, stream,
                       X, W, U, bg, Wd, bd, out);
}